// Round 11
// baseline (150.170 us; speedup 1.0000x reference)
//
#include <hip/hip_runtime.h>
#include <math.h>

// DIN fused pipeline, round 11: ONE block per batch, everything fused.
//  A: [blocks 0..255] q/u/targ bf16 projections (8 batches/block);
//     [block 256] Wk f32->bf16 (32 KB, L2-resident for B)
//  B: grid 2048, one block per batch. 4 quarters SERIAL inside the block,
//     16 KB LDS overlay per quarter (hist[64][128]bf16 <-> kT[200][40]bf16):
//       G: gather 64 clamped rows straight from f32 tables, inline RNE cvt
//       K: k-GEMM MFMA, k in 16 packed-bf16 VGPRs; fused hdot/tdot MFMA -> LDS
//       T: overlay kT stores (bijection f=200e+j per quarter, e in [32q,32q+32))
//       S: score partials q-slice x kT, accumulated in REGISTERS across quarters
//     then inline finalize: masked exp, beta=0.5 norm, pred, sigmoid -> out[b].
//  No table conversion pass, no memset, no atomics, no sp/hd/td global traffic.

#define HH 200
#define EE 128
#define KT_PITCH 40   // u16/row = 80 B (16B-aligned rows)

typedef float fp32x4 __attribute__((ext_vector_type(4)));
typedef short bf16x8 __attribute__((ext_vector_type(8)));

static __device__ __forceinline__ unsigned f2bf(float x) {
    unsigned u = __builtin_bit_cast(unsigned, x);
    return (u + 0x7FFFu + ((u >> 16) & 1u)) >> 16;   // RNE
}

// ---------------- Kernel A: projections + Wk conversion ----------------
__global__ __launch_bounds__(256) void prep_small(
    const int* __restrict__ target, const int* __restrict__ tregion,
    const float* __restrict__ embT, const float* __restrict__ embR,
    const float* __restrict__ Wq, const float* __restrict__ Wk,
    const float* __restrict__ Wv,
    unsigned short* __restrict__ dK,
    unsigned short* __restrict__ qbf, unsigned short* __restrict__ ubf,
    unsigned short* __restrict__ tbf)
{
    const int tid = threadIdx.x;
    if (blockIdx.x == 256) {
        // Wk: 16384 floats = 4096 float4; 16 per thread
        #pragma unroll
        for (int i = 0; i < 16; i++) {
            int j4 = i * 256 + tid;
            float4 v = *(const float4*)(Wk + 4 * (size_t)j4);
            ushort4 o;
            o.x = (unsigned short)f2bf(v.x); o.y = (unsigned short)f2bf(v.y);
            o.z = (unsigned short)f2bf(v.z); o.w = (unsigned short)f2bf(v.w);
            *(ushort4*)(dK + 4 * (size_t)j4) = o;
        }
        return;
    }

    __shared__ float st[8][128];
    const int b0 = blockIdx.x * 8;

    if (tid < 128) {
        int bb = tid >> 4, j = tid & 15;
        int b = b0 + bb;
        int ti = target[b], ri = tregion[b];
        *(float4*)&st[bb][j*4]      = *(const float4*)(embT + (size_t)ti*64 + j*4);
        *(float4*)&st[bb][64+j*4]   = *(const float4*)(embR + (size_t)ri*64 + j*4);
    }
    __syncthreads();

    if (tid < 128) {
        float acc[8] = {0,0,0,0,0,0,0,0};
        const float4* wr = (const float4*)(Wq + (size_t)tid*128);
        for (int e4 = 0; e4 < 32; e4++) {
            float4 w4 = wr[e4];
            #pragma unroll
            for (int bb = 0; bb < 8; bb++) {
                float4 t4 = *(const float4*)&st[bb][e4*4];
                acc[bb] += w4.x*t4.x + w4.y*t4.y + w4.z*t4.z + w4.w*t4.w;
            }
        }
        #pragma unroll
        for (int bb = 0; bb < 8; bb++) qbf[(size_t)(b0+bb)*128 + tid] = (unsigned short)f2bf(acc[bb]);
    } else {
        int e = tid - 128;
        float acc[8] = {0,0,0,0,0,0,0,0};
        for (int f = 0; f < 128; f++) {
            float wv = Wv[(size_t)f*128 + e];
            #pragma unroll
            for (int bb = 0; bb < 8; bb++) acc[bb] += st[bb][f] * wv;
        }
        #pragma unroll
        for (int bb = 0; bb < 8; bb++) ubf[(size_t)(b0+bb)*128 + e] = (unsigned short)f2bf(acc[bb]);
    }
    __syncthreads();
    {
        int bb = tid >> 5, x = (tid & 31) * 4;
        float4 t4 = *(const float4*)&st[bb][x];
        ushort4 o;
        o.x = (unsigned short)f2bf(t4.x); o.y = (unsigned short)f2bf(t4.y);
        o.z = (unsigned short)f2bf(t4.z); o.w = (unsigned short)f2bf(t4.w);
        *(ushort4*)&tbf[(size_t)(b0+bb)*128 + x] = o;
    }
}

// ---------------- Kernel B: one block per batch, fully fused ----------------
__global__ __launch_bounds__(256, 5) void din_fused(
    const int* __restrict__ history, const int* __restrict__ hregion,
    const float* __restrict__ embT, const float* __restrict__ embR,
    const unsigned short* __restrict__ wk, const unsigned short* __restrict__ qb,
    const unsigned short* __restrict__ ub, const unsigned short* __restrict__ tb,
    const int* __restrict__ target, const float* __restrict__ hvr,
    float* __restrict__ out)
{
    // per-quarter overlay: hist[64][128] bf16 swizzled (16384 B) <-> kT[200][40] (16000 B)
    __shared__ unsigned short smem[8192];
    __shared__ float s_hd[200], s_td[200], s_sc[200];
    __shared__ float s_red[4];

    const int b = blockIdx.x;
    const int tid = threadIdx.x;
    const int lane = tid & 63, w = tid >> 6;
    const int c = lane & 15, g = lane >> 4;
    const int e0 = 8 * g;

    // Wk B-fragments: wave w owns k-columns h in [32w, 32w+32)
    bf16x8 wkf[2][4];
    #pragma unroll
    for (int nt = 0; nt < 2; nt++)
        #pragma unroll
        for (int kc = 0; kc < 4; kc++)
            wkf[nt][kc] = *(const bf16x8*)(wk + (size_t)(32*w + 16*nt + c)*128 + kc*32 + e0);

    const unsigned short* utp = (c < 8 ? ub : tb) + (size_t)b*128;

    float scoreacc[4] = {0.f, 0.f, 0.f, 0.f};   // lane<16 holds j = (w+4*slot)*16 + lane

    #pragma unroll 1
    for (int qq = 0; qq < 4; qq++) {
        const int rbase = qq * 50;

        // ---- G: gather 64 clamped rows from f32 tables, inline cvt ----
        #pragma unroll
        for (int it = 0; it < 4; it++) {
            int r = it*16 + (tid >> 4);
            int j = tid & 15;
            int rr = (r < 50) ? r : 49;
            size_t rg = (size_t)b*200 + rbase + rr;
            const float* srcf;
            if (j < 8) { int ih = history[rg]; srcf = embT + (size_t)ih*64 + j*8; }
            else       { int ir = hregion[rg]; srcf = embR + (size_t)ir*64 + (j-8)*8; }
            float4 v0 = *(const float4*)srcf;
            float4 v1 = *(const float4*)(srcf + 4);
            uint4 pk;
            pk.x = f2bf(v0.x) | (f2bf(v0.y) << 16);
            pk.y = f2bf(v0.z) | (f2bf(v0.w) << 16);
            pk.z = f2bf(v1.x) | (f2bf(v1.y) << 16);
            pk.w = f2bf(v1.z) | (f2bf(v1.w) << 16);
            unsigned dst = ((unsigned)(r*256 + j*16)) ^ (((unsigned)(r & 7)) << 4);
            *(uint4*)((char*)smem + dst) = pk;
        }
        __syncthreads();

        // ---- K: 4 m-tiles; k in 16 packed-bf16 VGPRs; fused hdot/tdot (mt==w) ----
        unsigned kv[16];
        #pragma unroll
        for (int mt = 0; mt < 4; mt++) {
            const int ar = mt*16 + c;
            const unsigned swa = ((unsigned)(ar & 7)) << 4;
            bf16x8 a[4];
            #pragma unroll
            for (int kc = 0; kc < 4; kc++) {
                unsigned off = ((unsigned)(ar*256 + kc*64 + e0*2)) ^ swa;
                a[kc] = *(const bf16x8*)((const char*)smem + off);
            }
            fp32x4 acc0 = {0,0,0,0}, acc1 = {0,0,0,0};
            #pragma unroll
            for (int kc = 0; kc < 4; kc++) {
                acc0 = __builtin_amdgcn_mfma_f32_16x16x32_bf16(a[kc], wkf[0][kc], acc0, 0, 0, 0);
                acc1 = __builtin_amdgcn_mfma_f32_16x16x32_bf16(a[kc], wkf[1][kc], acc1, 0, 0, 0);
            }
            #pragma unroll
            for (int r = 0; r < 4; r++)
                kv[mt*4 + r] = f2bf(acc0[r]) | (f2bf(acc1[r]) << 16);

            if (mt == w) {
                fp32x4 hacc = {0,0,0,0};
                #pragma unroll
                for (int kc = 0; kc < 4; kc++) {
                    bf16x8 utf = *(const bf16x8*)(utp + kc*32 + e0);
                    hacc = __builtin_amdgcn_mfma_f32_16x16x32_bf16(a[kc], utf, hacc, 0, 0, 0);
                }
                if (c == 0 || c == 8) {
                    float* dst = (c == 0) ? s_hd : s_td;
                    const int slb = w*16 + 4*g;
                    #pragma unroll
                    for (int r = 0; r < 4; r++) {
                        int sl = slb + r;
                        if (sl < 50) dst[rbase + sl] = hacc[r];
                    }
                }
            }
        }
        __syncthreads();   // hist consumed; smem becomes kT

        // ---- T: kT stores: f = (rbase+sl)*128 + h; e_l = f/200 - 32q ----
        #pragma unroll
        for (int mt = 0; mt < 4; mt++) {
            const int slb = mt*16 + 4*g;
            #pragma unroll
            for (int r = 0; r < 4; r++) {
                int sl = slb + r;
                if (sl < 50) {
                    unsigned v = kv[mt*4 + r];
                    unsigned f  = (unsigned)((rbase + sl)*128 + 32*w + c);
                    unsigned e  = f / 200u;  unsigned j  = f - e*200u;
                    smem[j*KT_PITCH + (e - (unsigned)(qq<<5))] = (unsigned short)v;
                    unsigned f2 = f + 16u;
                    unsigned e2 = f2 / 200u; unsigned j2 = f2 - e2*200u;
                    smem[j2*KT_PITCH + (e2 - (unsigned)(qq<<5))] = (unsigned short)(v >> 16);
                }
            }
        }
        __syncthreads();

        // ---- S: score partials into registers (one K=32 MFMA per j-tile) ----
        const bf16x8 af = *(const bf16x8*)(qb + (size_t)b*128 + (qq<<5) + e0);
        int slot = 0;
        for (int jt = w; jt < 13; jt += 4, slot++) {
            int jr = jt*16 + c; if (jr > 199) jr = 199;
            bf16x8 bfr = *(const bf16x8*)&smem[(unsigned)jr*KT_PITCH + e0];
            fp32x4 sacc = {0,0,0,0};
            sacc = __builtin_amdgcn_mfma_f32_16x16x32_bf16(af, bfr, sacc, 0, 0, 0);
            scoreacc[slot] += sacc[0];
        }
        __syncthreads();   // kT consumed before next quarter's G overwrites
    }

    // ---- inline finalize ----
    {
        int slot = 0;
        for (int jt = w; jt < 13; jt += 4, slot++) {
            if (lane < 16) {
                int j = jt*16 + lane;
                if (j < 200) s_sc[j] = scoreacc[slot];
            }
        }
    }
    __syncthreads();

    const int tgt = target[b];
    float ev = 0.f;
    if (tid < 200) {
        int uh = history[(size_t)b*200 + tid];
        ev = (uh != tgt) ? expf(s_sc[tid] * 0.088388347648318447f) : 0.f;
    }
    float sum = ev;
    #pragma unroll
    for (int m = 1; m < 64; m <<= 1) sum += __shfl_xor(sum, m, 64);
    if (lane == 0) s_red[w] = sum;
    __syncthreads();
    float total = (s_red[0] + s_red[1]) + (s_red[2] + s_red[3]);

    float pv = 0.f;
    if (tid < 200) {
        float attn = ev * rsqrtf(total);          // exp_A / sum^0.5
        pv = attn * s_hd[tid] + hvr[tid] * s_td[tid];
    }
    float ps = pv;
    #pragma unroll
    for (int m = 1; m < 64; m <<= 1) ps += __shfl_xor(ps, m, 64);
    if (lane == 0) s_red[w] = ps;
    __syncthreads();
    if (tid == 0) {
        float pred = (s_red[0] + s_red[1]) + (s_red[2] + s_red[3]);
        out[b] = 1.0f / (1.0f + expf(-pred));
    }
}

extern "C" void kernel_launch(void* const* d_in, const int* in_sizes, int n_in,
                              void* d_out, int out_size, void* d_ws, size_t ws_size,
                              hipStream_t stream) {
    const int*   history = (const int*)d_in[0];
    const int*   target  = (const int*)d_in[1];
    const int*   hregion = (const int*)d_in[2];
    const int*   tregion = (const int*)d_in[3];
    const float* hvrate  = (const float*)d_in[4];
    const float* embT    = (const float*)d_in[5];
    const float* embR    = (const float*)d_in[6];
    const float* Wq      = (const float*)d_in[7];
    const float* Wk      = (const float*)d_in[8];
    const float* Wv      = (const float*)d_in[9];
    float* outp = (float*)d_out;

    char* ws = (char*)d_ws;
    unsigned short* dK = (unsigned short*)(ws);                 //     32,768
    unsigned short* qb = (unsigned short*)(ws + 32768);         //    524,288
    unsigned short* ub = (unsigned short*)(ws + 557056);        //    524,288
    unsigned short* tb = (unsigned short*)(ws + 1081344);       //    524,288  (end 1,605,632)

    hipLaunchKernelGGL(prep_small, dim3(257), dim3(256), 0, stream,
                       target, tregion, embT, embR, Wq, Wk, Wv,
                       dK, qb, ub, tb);
    hipLaunchKernelGGL(din_fused, dim3(2048), dim3(256), 0, stream,
                       history, hregion, embT, embR, dK, qb, ub, tb,
                       target, hvrate, outp);
}

// Round 12
// 68.963 us; speedup vs baseline: 2.1776x; 2.1776x over previous
//
#include <hip/hip_runtime.h>
#include <math.h>

// DIN fused pipeline, round 12: serial-quarter fused kernel + global_load_lds
// double-buffered gather + restored bf16 table conversion (L3 residency!).
//  prep: [blocks 0..2047] convert embT/embR f32->bf16 + Wk ; [2048..2303] q/u/targ bf16
//  B: grid 2048, one block per batch, 4 quarters serial:
//     issue gather(q+1) via global_load_lds -> other buffer (async, hidden under K)
//     K: k-GEMM MFMA from cur buffer -> kv regs; fused hdot/tdot MFMA -> LDS
//     T: overlay cur as kT[j][e_l] (bijection f=200e+j, e in [32q,32q+32))
//     S: score partials q-slice x kT -> register accumulators
//     inline finalize: masked exp, beta=0.5 norm, pred, sigmoid -> out[b]
//  Gather swizzle folded into GLOBAL source chunk (cj = j ^ (row&7)); LDS dest linear.

#define HH 200
#define EE 128
#define KT_PITCH 40   // u16/row = 80 B (16B-aligned rows; 2-way banks on reads/stores)

typedef float fp32x4 __attribute__((ext_vector_type(4)));
typedef short bf16x8 __attribute__((ext_vector_type(8)));

static __device__ __forceinline__ unsigned f2bf(float x) {
    unsigned u = __builtin_bit_cast(unsigned, x);
    return (u + 0x7FFFu + ((u >> 16) & 1u)) >> 16;   // RNE
}

// ---------------- Kernel prep: table conversion + q/u/targ projection ----------------
#define N4_T 1600000   // embT float4 units (100000*64/4)
#define N4_R 16000     // embR
#define N4_K 4096      // Wk
#define N4_ALL (N4_T + N4_R + N4_K)
#define CONV_BLOCKS 2048
#define CONV_THREADS (CONV_BLOCKS * 256)

__global__ __launch_bounds__(256) void prep(
    const int* __restrict__ target, const int* __restrict__ tregion,
    const float* __restrict__ embT, const float* __restrict__ embR,
    const float* __restrict__ Wq, const float* __restrict__ Wk,
    const float* __restrict__ Wv,
    unsigned short* __restrict__ dT, unsigned short* __restrict__ dR,
    unsigned short* __restrict__ dK,
    unsigned short* __restrict__ qbf, unsigned short* __restrict__ ubf,
    unsigned short* __restrict__ tbf)
{
    const int tid = threadIdx.x;
    if (blockIdx.x < CONV_BLOCKS) {
        int idx = blockIdx.x * 256 + tid;
        for (int i = idx; i < N4_ALL; i += CONV_THREADS) {
            const float* src; unsigned short* dst;
            if (i < N4_T)             { src = embT + 4*(size_t)i;            dst = dT + 4*(size_t)i; }
            else if (i < N4_T + N4_R) { int j = i - N4_T;        src = embR + 4*(size_t)j; dst = dR + 4*(size_t)j; }
            else                      { int j = i - N4_T - N4_R; src = Wk   + 4*(size_t)j; dst = dK + 4*(size_t)j; }
            float4 v = *(const float4*)src;
            ushort4 o;
            o.x = (unsigned short)f2bf(v.x); o.y = (unsigned short)f2bf(v.y);
            o.z = (unsigned short)f2bf(v.z); o.w = (unsigned short)f2bf(v.w);
            *(ushort4*)dst = o;
        }
        return;
    }

    // projection role: 8 batches per block
    __shared__ float st[8][128];
    const int b0 = (blockIdx.x - CONV_BLOCKS) * 8;

    if (tid < 128) {
        int bb = tid >> 4, j = tid & 15;
        int b = b0 + bb;
        int ti = target[b], ri = tregion[b];
        *(float4*)&st[bb][j*4]      = *(const float4*)(embT + (size_t)ti*64 + j*4);
        *(float4*)&st[bb][64+j*4]   = *(const float4*)(embR + (size_t)ri*64 + j*4);
    }
    __syncthreads();

    if (tid < 128) {
        float acc[8] = {0,0,0,0,0,0,0,0};
        const float4* wr = (const float4*)(Wq + (size_t)tid*128);
        for (int e4 = 0; e4 < 32; e4++) {
            float4 w4 = wr[e4];
            #pragma unroll
            for (int bb = 0; bb < 8; bb++) {
                float4 t4 = *(const float4*)&st[bb][e4*4];
                acc[bb] += w4.x*t4.x + w4.y*t4.y + w4.z*t4.z + w4.w*t4.w;
            }
        }
        #pragma unroll
        for (int bb = 0; bb < 8; bb++) qbf[(size_t)(b0+bb)*128 + tid] = (unsigned short)f2bf(acc[bb]);
    } else {
        int e = tid - 128;
        float acc[8] = {0,0,0,0,0,0,0,0};
        for (int f = 0; f < 128; f++) {
            float wv = Wv[(size_t)f*128 + e];
            #pragma unroll
            for (int bb = 0; bb < 8; bb++) acc[bb] += st[bb][f] * wv;
        }
        #pragma unroll
        for (int bb = 0; bb < 8; bb++) ubf[(size_t)(b0+bb)*128 + e] = (unsigned short)f2bf(acc[bb]);
    }
    __syncthreads();
    {
        int bb = tid >> 5, x = (tid & 31) * 4;
        float4 t4 = *(const float4*)&st[bb][x];
        ushort4 o;
        o.x = (unsigned short)f2bf(t4.x); o.y = (unsigned short)f2bf(t4.y);
        o.z = (unsigned short)f2bf(t4.z); o.w = (unsigned short)f2bf(t4.w);
        *(ushort4*)&tbf[(size_t)(b0+bb)*128 + x] = o;
    }
}

// ---------------- Kernel B: fused, double-buffered global_load_lds gather ----------------
__global__ __launch_bounds__(256, 4) void din_fused(
    const int* __restrict__ history, const int* __restrict__ hregion,
    const unsigned short* __restrict__ dT, const unsigned short* __restrict__ dR,
    const unsigned short* __restrict__ wk, const unsigned short* __restrict__ qb,
    const unsigned short* __restrict__ ub, const unsigned short* __restrict__ tb,
    const int* __restrict__ target, const float* __restrict__ hvr,
    float* __restrict__ out)
{
    __shared__ unsigned short bufA[8192];   // hist[64][128] linear (swizzle in source) / kT overlay
    __shared__ unsigned short bufB[8192];
    __shared__ int   s_ih[200], s_ir[200];
    __shared__ float s_hd[200], s_td[200], s_sc[200];
    __shared__ float s_red[4];

    const int b = blockIdx.x;
    const int tid = threadIdx.x;
    const int lane = tid & 63, w = tid >> 6;
    const int c = lane & 15, g = lane >> 4;
    const int e0 = 8 * g;

    // index preload (kills idx->row chained latency in the gather)
    if (tid < 200) {
        s_ih[tid] = history[(size_t)b*200 + tid];
        s_ir[tid] = hregion[(size_t)b*200 + tid];
    }

    // Wk B-fragments: wave w owns k-columns h in [32w, 32w+32)
    bf16x8 wkf[2][4];
    #pragma unroll
    for (int nt = 0; nt < 2; nt++)
        #pragma unroll
        for (int kc = 0; kc < 4; kc++)
            wkf[nt][kc] = *(const bf16x8*)(wk + (size_t)(32*w + 16*nt + c)*128 + kc*32 + e0);

    const unsigned short* utp = (c < 8 ? ub : tb) + (size_t)b*128;
    __syncthreads();   // s_ih/s_ir visible

    // gather issue: 4 x global_load_lds(16B); LDS dest linear in lane;
    // bank swizzle folded into the global source chunk index.
    auto gather_issue = [&](int qq, unsigned short* dst) {
        const int rb = qq * 50;
        #pragma unroll
        for (int it = 0; it < 4; it++) {
            int row = it*16 + (tid >> 4);
            int rr  = (row < 50) ? row : 49;     // rows 50..63 duplicate 49 (pad)
            int cj  = (tid & 15) ^ (row & 7);    // pre-swizzled source chunk
            const unsigned short* src = (cj < 8)
                ? dT + (size_t)s_ih[rb + rr]*64 + cj*8
                : dR + (size_t)s_ir[rb + rr]*64 + (cj-8)*8;
            __builtin_amdgcn_global_load_lds(
                (const __attribute__((address_space(1))) unsigned int*)src,
                (__attribute__((address_space(3))) unsigned int*)(dst + (size_t)row*128 + (tid & 15)*8),
                16, 0, 0);
        }
    };

    gather_issue(0, bufA);
    __syncthreads();   // vmcnt drained by barrier semantics -> hist(0) ready

    unsigned short* cur = bufA;
    unsigned short* nxt = bufB;
    float scoreacc[4] = {0.f, 0.f, 0.f, 0.f};

    #pragma unroll 1
    for (int qq = 0; qq < 4; qq++) {
        const int rbase = qq * 50;
        if (qq < 3) gather_issue(qq + 1, nxt);   // async; drains at K-end barrier

        // ---- K: 4 m-tiles; k in 16 packed-bf16 VGPRs; fused hdot/tdot (mt==w) ----
        unsigned kv[16];
        #pragma unroll
        for (int mt = 0; mt < 4; mt++) {
            const int ar = mt*16 + c;
            const unsigned swa = ((unsigned)(ar & 7)) << 4;
            bf16x8 a[4];
            #pragma unroll
            for (int kc = 0; kc < 4; kc++) {
                unsigned off = ((unsigned)(ar*256 + kc*64 + e0*2)) ^ swa;
                a[kc] = *(const bf16x8*)((const char*)cur + off);
            }
            fp32x4 acc0 = {0,0,0,0}, acc1 = {0,0,0,0};
            #pragma unroll
            for (int kc = 0; kc < 4; kc++) {
                acc0 = __builtin_amdgcn_mfma_f32_16x16x32_bf16(a[kc], wkf[0][kc], acc0, 0, 0, 0);
                acc1 = __builtin_amdgcn_mfma_f32_16x16x32_bf16(a[kc], wkf[1][kc], acc1, 0, 0, 0);
            }
            #pragma unroll
            for (int r = 0; r < 4; r++)
                kv[mt*4 + r] = f2bf(acc0[r]) | (f2bf(acc1[r]) << 16);

            if (mt == w) {
                fp32x4 hacc = {0,0,0,0};
                #pragma unroll
                for (int kc = 0; kc < 4; kc++) {
                    bf16x8 utf = *(const bf16x8*)(utp + kc*32 + e0);
                    hacc = __builtin_amdgcn_mfma_f32_16x16x32_bf16(a[kc], utf, hacc, 0, 0, 0);
                }
                if (c == 0 || c == 8) {
                    float* dst = (c == 0) ? s_hd : s_td;
                    const int slb = w*16 + 4*g;
                    #pragma unroll
                    for (int r = 0; r < 4; r++) {
                        int sl = slb + r;
                        if (sl < 50) dst[rbase + sl] = hacc[r];
                    }
                }
            }
        }
        __syncthreads();   // hist consumed (also drains next-q gather)

        // ---- T: kT stores into cur: f = (rbase+sl)*128 + h; e_l = f/200 - 32q ----
        #pragma unroll
        for (int mt = 0; mt < 4; mt++) {
            const int slb = mt*16 + 4*g;
            #pragma unroll
            for (int r = 0; r < 4; r++) {
                int sl = slb + r;
                if (sl < 50) {
                    unsigned v = kv[mt*4 + r];
                    unsigned f  = (unsigned)((rbase + sl)*128 + 32*w + c);
                    unsigned e  = f / 200u;  unsigned j  = f - e*200u;
                    cur[j*KT_PITCH + (e - (unsigned)(qq<<5))] = (unsigned short)v;
                    unsigned f2 = f + 16u;
                    unsigned e2 = f2 / 200u; unsigned j2 = f2 - e2*200u;
                    cur[j2*KT_PITCH + (e2 - (unsigned)(qq<<5))] = (unsigned short)(v >> 16);
                }
            }
        }
        __syncthreads();

        // ---- S: score partials into registers (one K=32 MFMA per j-tile) ----
        const bf16x8 af = *(const bf16x8*)(qb + (size_t)b*128 + (qq<<5) + e0);
        int slot = 0;
        for (int jt = w; jt < 13; jt += 4, slot++) {
            int jr = jt*16 + c; if (jr > 199) jr = 199;
            bf16x8 bfr = *(const bf16x8*)&cur[(unsigned)jr*KT_PITCH + e0];
            fp32x4 sacc = {0,0,0,0};
            sacc = __builtin_amdgcn_mfma_f32_16x16x32_bf16(af, bfr, sacc, 0, 0, 0);
            scoreacc[slot] += sacc[0];
        }
        __syncthreads();   // kT consumed; cur free to become next gather target

        unsigned short* t = cur; cur = nxt; nxt = t;
    }

    // ---- inline finalize ----
    {
        int slot = 0;
        for (int jt = w; jt < 13; jt += 4, slot++) {
            if (lane < 16) {
                int j = jt*16 + lane;
                if (j < 200) s_sc[j] = scoreacc[slot];
            }
        }
    }
    __syncthreads();

    const int tgt = target[b];
    float ev = 0.f;
    if (tid < 200) {
        ev = (s_ih[tid] != tgt) ? expf(s_sc[tid] * 0.088388347648318447f) : 0.f;
    }
    float sum = ev;
    #pragma unroll
    for (int m = 1; m < 64; m <<= 1) sum += __shfl_xor(sum, m, 64);
    if (lane == 0) s_red[w] = sum;
    __syncthreads();
    float total = (s_red[0] + s_red[1]) + (s_red[2] + s_red[3]);

    float pv = 0.f;
    if (tid < 200) {
        float attn = ev * rsqrtf(total);          // exp_A / sum^0.5
        pv = attn * s_hd[tid] + hvr[tid] * s_td[tid];
    }
    float ps = pv;
    #pragma unroll
    for (int m = 1; m < 64; m <<= 1) ps += __shfl_xor(ps, m, 64);
    if (lane == 0) s_red[w] = ps;
    __syncthreads();
    if (tid == 0) {
        float pred = (s_red[0] + s_red[1]) + (s_red[2] + s_red[3]);
        out[b] = 1.0f / (1.0f + expf(-pred));
    }
}

extern "C" void kernel_launch(void* const* d_in, const int* in_sizes, int n_in,
                              void* d_out, int out_size, void* d_ws, size_t ws_size,
                              hipStream_t stream) {
    const int*   history = (const int*)d_in[0];
    const int*   target  = (const int*)d_in[1];
    const int*   hregion = (const int*)d_in[2];
    const int*   tregion = (const int*)d_in[3];
    const float* hvrate  = (const float*)d_in[4];
    const float* embT    = (const float*)d_in[5];
    const float* embR    = (const float*)d_in[6];
    const float* Wq      = (const float*)d_in[7];
    const float* Wk      = (const float*)d_in[8];
    const float* Wv      = (const float*)d_in[9];
    float* outp = (float*)d_out;

    char* ws = (char*)d_ws;
    unsigned short* dT = (unsigned short*)(ws);                 // 12,800,000 B
    unsigned short* dR = (unsigned short*)(ws + 12800000);      //    128,000
    unsigned short* dK = (unsigned short*)(ws + 12928000);      //     32,768
    unsigned short* ub = (unsigned short*)(ws + 12960768);      //    524,288
    unsigned short* tb = (unsigned short*)(ws + 13485056);      //    524,288
    unsigned short* qb = (unsigned short*)(ws + 14009344);      //    524,288  (end 14,533,632)

    hipLaunchKernelGGL(prep, dim3(CONV_BLOCKS + 256), dim3(256), 0, stream,
                       target, tregion, embT, embR, Wq, Wk, Wv,
                       dT, dR, dK, qb, ub, tb);
    hipLaunchKernelGGL(din_fused, dim3(2048), dim3(256), 0, stream,
                       history, hregion, dT, dR, dK, qb, ub, tb,
                       target, hvrate, outp);
}